// Round 1
// baseline (6152.396 us; speedup 1.0000x reference)
//
#include <hip/hip_runtime.h>
#include <math.h>

#define NN 100000
#define NG 256

// ---------------- degree / norm ----------------
__global__ void init_deg(float* deg, int n) {
    int i = blockIdx.x * blockDim.x + threadIdx.x;
    if (i < n) deg[i] = 1.0f;  // self-loop contributes 1
}

__global__ void count_deg(const int* __restrict__ dst, float* deg, int e) {
    int i = blockIdx.x * blockDim.x + threadIdx.x;
    if (i < e) atomicAdd(&deg[dst[i]], 1.0f);
}

__global__ void make_dinv(float* deg, int n) {
    int i = blockIdx.x * blockDim.x + threadIdx.x;
    if (i < n) deg[i] = 1.0f / sqrtf(deg[i]);  // deg >= 1 always
}

// ---------------- fused transform + self-loop init ----------------
// t[i][f]   = act(xin[i]) @ W  (+relu on input if RELU_IN)
// agg[i][f] = t[i][f] * dinv[i]^2 + b[f]       (self-loop + bias init)
template<int K, int DOUT, bool RELU_IN>
__global__ void transform(const float* __restrict__ xin,
                          const float* __restrict__ W,
                          const float* __restrict__ b,
                          const float* __restrict__ dinv,
                          float* __restrict__ t,
                          float* __restrict__ agg, int n) {
    int tid = blockIdx.x * blockDim.x + threadIdx.x;
    int i = tid / DOUT;
    int f = tid % DOUT;
    if (i >= n) return;
    const float* row = xin + (size_t)i * K;
    float acc = 0.0f;
#pragma unroll
    for (int k = 0; k < K; ++k) {
        float v = row[k];                      // wave-uniform (broadcast) load
        if (RELU_IN) v = fmaxf(v, 0.0f);
        acc = fmaf(v, W[k * DOUT + f], acc);   // coalesced across lanes
    }
    size_t o = (size_t)i * DOUT + f;
    t[o] = acc;
    float di = dinv[i];
    agg[o] = acc * di * di + b[f];
}

// ---------------- per-edge scatter-add ----------------
// thread = (edge, 4-float chunk); chunk varies fastest -> coalesced t-row read
template<int DOUT>
__global__ void edge_scatter(const int* __restrict__ src,
                             const int* __restrict__ dst,
                             const float* __restrict__ dinv,
                             const float* __restrict__ t,
                             float* __restrict__ agg, int e) {
    const int C = DOUT / 4;
    int tid = blockIdx.x * blockDim.x + threadIdx.x;
    int eidx = tid / C;
    int c = tid % C;
    if (eidx >= e) return;
    int s = src[eidx];
    int d = dst[eidx];
    float w = dinv[s] * dinv[d];
    float4 v = *(const float4*)(t + (size_t)s * DOUT + c * 4);
    float* out = agg + (size_t)d * DOUT + c * 4;
    atomicAdd(out + 0, v.x * w);
    atomicAdd(out + 1, v.y * w);
    atomicAdd(out + 2, v.z * w);
    atomicAdd(out + 3, v.w * w);
}

// ---------------- pooling ----------------
__global__ void pool_zero(float* gs, float* cnt) {
    int i = blockIdx.x * blockDim.x + threadIdx.x;
    if (i < NG * 64) gs[i] = 0.0f;
    if (i < NG) cnt[i] = 0.0f;
}

__global__ void pool_acc(const float* __restrict__ agg3,
                         const int* __restrict__ batch,
                         float* gs, float* cnt, int n) {
    int tid = blockIdx.x * blockDim.x + threadIdx.x;
    int i = tid / 64;
    int f = tid % 64;
    if (i >= n) return;
    float v = fmaxf(agg3[(size_t)i * 64 + f], 0.0f);  // relu of layer-3 output
    int g = batch[i];
    atomicAdd(&gs[g * 64 + f], v);
    if (f == 0) atomicAdd(&cnt[g], 1.0f);
}

__global__ void pool_final(const float* __restrict__ gs,
                           const float* __restrict__ cnt,
                           const float* __restrict__ Wfc,
                           const float* __restrict__ bfc,
                           float* __restrict__ out) {
    int g = blockIdx.x * blockDim.x + threadIdx.x;
    if (g >= NG) return;
    float c = fmaxf(cnt[g], 1.0f);
    float s = 0.0f;
    for (int f = 0; f < 64; ++f) s += (gs[g * 64 + f] / c) * Wfc[f];
    s += bfc[0];
    out[g] = 1.0f / (1.0f + expf(-s));
}

static inline int cdiv(long long a, int b) { return (int)((a + b - 1) / b); }

extern "C" void kernel_launch(void* const* d_in, const int* in_sizes, int n_in,
                              void* d_out, int out_size, void* d_ws, size_t ws_size,
                              hipStream_t stream) {
    const float* x   = (const float*)d_in[0];
    const int*   ei  = (const int*)d_in[1];
    const int*   bat = (const int*)d_in[2];
    const float* W1  = (const float*)d_in[3];
    const float* b1  = (const float*)d_in[4];
    const float* W2  = (const float*)d_in[5];
    const float* b2  = (const float*)d_in[6];
    const float* W3  = (const float*)d_in[7];
    const float* b3  = (const float*)d_in[8];
    const float* Wfc = (const float*)d_in[9];
    const float* bfc = (const float*)d_in[10];
    float* out = (float*)d_out;

    const int N = in_sizes[0] / 5;          // 100000
    const int E = in_sizes[1] / 2;          // 1600000
    const int* src = ei;
    const int* dst = ei + E;

    // workspace layout (floats); all offsets multiples of 4 floats (16B align)
    float* ws   = (float*)d_ws;
    float* dinv = ws;                        // N
    float* tbuf = dinv + NN;                 // N*128 (max width)
    float* aggA = tbuf + (size_t)NN * 128;   // N*64   (layers 1 and 3)
    float* aggB = aggA + (size_t)NN * 64;    // N*128  (layer 2)
    float* gs   = aggB + (size_t)NN * 128;   // 256*64
    float* cnt  = gs + NG * 64;              // 256

    const int B = 256;

    // norm
    init_deg<<<cdiv(N, B), B, 0, stream>>>(dinv, N);
    count_deg<<<cdiv(E, B), B, 0, stream>>>(dst, dinv, E);
    make_dinv<<<cdiv(N, B), B, 0, stream>>>(dinv, N);

    // layer 1: 5 -> 64
    transform<5, 64, false><<<cdiv((long long)N * 64, B), B, 0, stream>>>(
        x, W1, b1, dinv, tbuf, aggA, N);
    edge_scatter<64><<<cdiv((long long)E * 16, B), B, 0, stream>>>(
        src, dst, dinv, tbuf, aggA, E);

    // layer 2: 64 -> 128 (relu on input)
    transform<64, 128, true><<<cdiv((long long)N * 128, B), B, 0, stream>>>(
        aggA, W2, b2, dinv, tbuf, aggB, N);
    edge_scatter<128><<<cdiv((long long)E * 32, B), B, 0, stream>>>(
        src, dst, dinv, tbuf, aggB, E);

    // layer 3: 128 -> 64 (relu on input)
    transform<128, 64, true><<<cdiv((long long)N * 64, B), B, 0, stream>>>(
        aggB, W3, b3, dinv, tbuf, aggA, N);
    edge_scatter<64><<<cdiv((long long)E * 16, B), B, 0, stream>>>(
        src, dst, dinv, tbuf, aggA, E);

    // pooling + head
    pool_zero<<<cdiv(NG * 64, B), B, 0, stream>>>(gs, cnt);
    pool_acc<<<cdiv((long long)N * 64, B), B, 0, stream>>>(aggA, bat, gs, cnt, N);
    pool_final<<<1, NG, 0, stream>>>(gs, cnt, Wfc, bfc, out);
}

// Round 2
// 1098.403 us; speedup vs baseline: 5.6012x; 5.6012x over previous
//
#include <hip/hip_runtime.h>
#include <math.h>

#define NG 256

// ---------------- degree / cursor init ----------------
__global__ void zero2(int* deg, int* cursor, int n) {
    int i = blockIdx.x * blockDim.x + threadIdx.x;
    if (i < n) { deg[i] = 0; cursor[i] = 0; }
}

__global__ void hist(const int* __restrict__ dst, int* deg, int e) {
    int i = blockIdx.x * blockDim.x + threadIdx.x;
    if (i < e) atomicAdd(&deg[dst[i]], 1);
}

__global__ void make_dinv(const int* __restrict__ deg, float* dinv, int n) {
    int i = blockIdx.x * blockDim.x + threadIdx.x;
    if (i < n) dinv[i] = rsqrtf((float)deg[i] + 1.0f);  // +1 self-loop
}

// ---------------- exclusive scan of deg -> rowptr ----------------
__global__ void scan_blk(const int* __restrict__ deg, int* rowptr,
                         int* blksum, int n) {
    __shared__ int sh[1024];
    int tid = threadIdx.x;
    int g = blockIdx.x * 1024 + tid;
    int v = (g < n) ? deg[g] : 0;
    sh[tid] = v;
    __syncthreads();
    for (int off = 1; off < 1024; off <<= 1) {
        int t = (tid >= off) ? sh[tid - off] : 0;
        __syncthreads();
        sh[tid] += t;
        __syncthreads();
    }
    if (g < n) rowptr[g + 1] = sh[tid];            // block-local inclusive
    if (tid == 1023) blksum[blockIdx.x] = sh[1023];
}

__global__ void scan_sums(int* blksum, int nb) {
    if (blockIdx.x == 0 && threadIdx.x == 0) {
        int run = 0;
        for (int b = 0; b < nb; ++b) { run += blksum[b]; blksum[b] = run; }
    }
}

__global__ void scan_add(int* rowptr, const int* __restrict__ blksum, int n) {
    int g = blockIdx.x * blockDim.x + threadIdx.x;
    if (g == 0) rowptr[0] = 0;
    if (g < n) {
        int b = g >> 10;
        if (b > 0) rowptr[g + 1] += blksum[b - 1];
    }
}

// ---------------- CSR fill (src list + precomputed edge weight) ----------
__global__ void fill_csr(const int* __restrict__ src, const int* __restrict__ dst,
                         const float* __restrict__ dinv,
                         const int* __restrict__ rowptr, int* cursor,
                         int* csr_src, float* csr_w, int e) {
    int i = blockIdx.x * blockDim.x + threadIdx.x;
    if (i >= e) return;
    int s = src[i], d = dst[i];
    int pos = rowptr[d] + atomicAdd(&cursor[d], 1);
    csr_src[pos] = s;
    csr_w[pos] = dinv[s] * dinv[d];
}

// ---------------- dense transform t = xin @ W ----------------
// thread = (node, out-feature); row loads are wave-uniform (broadcast)
template<int K, int DOUT>
__global__ void transform(const float* __restrict__ xin,
                          const float* __restrict__ W,
                          float* __restrict__ t, int n) {
    int tid = blockIdx.x * blockDim.x + threadIdx.x;
    int i = tid / DOUT;
    int f = tid % DOUT;
    if (i >= n) return;
    const float* row = xin + (size_t)i * K;
    float acc = 0.0f;
#pragma unroll
    for (int k = 0; k < K; ++k)
        acc = fmaf(row[k], W[k * DOUT + f], acc);
    t[(size_t)i * DOUT + f] = acc;
}

// ---------------- per-node gather: h = relu(bias + self + sum_in) --------
// wave owns 64 features of one node; contiguous 256B t-row reads; no atomics
template<int DOUT>
__global__ void gather(const int* __restrict__ rowptr,
                       const int* __restrict__ csr_src,
                       const float* __restrict__ csr_w,
                       const float* __restrict__ dinv,
                       const float* __restrict__ b,
                       const float* __restrict__ t,
                       float* __restrict__ h, int n) {
    int tid = blockIdx.x * blockDim.x + threadIdx.x;
    int i = tid / DOUT;
    int f = tid % DOUT;
    if (i >= n) return;
    float di = dinv[i];
    float acc = t[(size_t)i * DOUT + f] * di * di + b[f];
    int j = rowptr[i], end = rowptr[i + 1];
    for (; j + 1 < end; j += 2) {
        int s0 = csr_src[j], s1 = csr_src[j + 1];
        float w0 = csr_w[j], w1 = csr_w[j + 1];
        float v0 = t[(size_t)s0 * DOUT + f];
        float v1 = t[(size_t)s1 * DOUT + f];
        acc = fmaf(w0, v0, acc);
        acc = fmaf(w1, v1, acc);
    }
    if (j < end)
        acc = fmaf(csr_w[j], t[(size_t)csr_src[j] * DOUT + f], acc);
    h[(size_t)i * DOUT + f] = fmaxf(acc, 0.0f);
}

// ---------------- pooling + FC + sigmoid, one block per graph -----------
__global__ void pool(const float* __restrict__ h3, const int* __restrict__ batch,
                     const float* __restrict__ Wfc, const float* __restrict__ bfc,
                     float* __restrict__ out, int n) {
    int g = blockIdx.x;
    int lane = threadIdx.x;  // 64 threads = 1 wave = 64 features
    // lower_bound(batch, g) and lower_bound(batch, g+1): batch is sorted
    int lo = 0, hi = n;
    while (lo < hi) { int m = (lo + hi) >> 1; if (batch[m] < g) lo = m + 1; else hi = m; }
    int start = lo;
    hi = n;
    while (lo < hi) { int m = (lo + hi) >> 1; if (batch[m] < g + 1) lo = m + 1; else hi = m; }
    int end = lo;
    float acc = 0.0f;
    for (int m = start; m < end; ++m)
        acc += h3[(size_t)m * 64 + lane];
    float cnt = (float)(end - start);
    float val = acc / fmaxf(cnt, 1.0f);
    float v = val * Wfc[lane];
#pragma unroll
    for (int off = 32; off > 0; off >>= 1) v += __shfl_down(v, off, 64);
    if (lane == 0) out[g] = 1.0f / (1.0f + expf(-(v + bfc[0])));
}

static inline int cdiv(long long a, int b) { return (int)((a + b - 1) / b); }

extern "C" void kernel_launch(void* const* d_in, const int* in_sizes, int n_in,
                              void* d_out, int out_size, void* d_ws, size_t ws_size,
                              hipStream_t stream) {
    const float* x   = (const float*)d_in[0];
    const int*   ei  = (const int*)d_in[1];
    const int*   bat = (const int*)d_in[2];
    const float* W1  = (const float*)d_in[3];
    const float* b1  = (const float*)d_in[4];
    const float* W2  = (const float*)d_in[5];
    const float* b2  = (const float*)d_in[6];
    const float* W3  = (const float*)d_in[7];
    const float* b3  = (const float*)d_in[8];
    const float* Wfc = (const float*)d_in[9];
    const float* bfc = (const float*)d_in[10];
    float* out = (float*)d_out;

    const int N = in_sizes[0] / 5;   // 100000
    const int E = in_sizes[1] / 2;   // 1600000
    const int* src = ei;
    const int* dst = ei + E;

    // ---- workspace layout (4B elements, all 16B-aligned) ----
    float* ws    = (float*)d_ws;
    float* dinv  = ws;                         // N
    int*   deg   = (int*)(dinv + N);           // N
    int*   rowptr= deg + N;                    // N+1 (pad to N+4)
    int*   cursor= rowptr + N + 4;             // N
    int*   blksum= cursor + N;                 // 128
    int*   csrs  = blksum + 128;               // E
    float* csrw  = (float*)(csrs + E);         // E
    float* P1    = csrw + E;                   // N*128 (t buffers)
    float* P2    = P1 + (size_t)N * 128;       // N*128 (h buffers, reused)
    // total ~116 MB

    const int B = 256;
    const int NB = cdiv(N, 1024);

    // ---- norm + CSR build ----
    zero2<<<cdiv(N, B), B, 0, stream>>>(deg, cursor, N);
    hist<<<cdiv(E, B), B, 0, stream>>>(dst, deg, E);
    make_dinv<<<cdiv(N, B), B, 0, stream>>>(deg, dinv, N);
    scan_blk<<<NB, 1024, 0, stream>>>(deg, rowptr, blksum, N);
    scan_sums<<<1, 64, 0, stream>>>(blksum, NB);
    scan_add<<<cdiv(N, B), B, 0, stream>>>(rowptr, blksum, N);
    fill_csr<<<cdiv(E, B), B, 0, stream>>>(src, dst, dinv, rowptr, cursor,
                                           csrs, csrw, E);

    // ---- layer 1: 5 -> 64 ----
    transform<5, 64><<<cdiv((long long)N * 64, B), B, 0, stream>>>(x, W1, P1, N);
    gather<64><<<cdiv((long long)N * 64, B), B, 0, stream>>>(
        rowptr, csrs, csrw, dinv, b1, P1, P2, N);      // h1 -> P2

    // ---- layer 2: 64 -> 128 ----
    transform<64, 128><<<cdiv((long long)N * 128, B), B, 0, stream>>>(P2, W2, P1, N);
    gather<128><<<cdiv((long long)N * 128, B), B, 0, stream>>>(
        rowptr, csrs, csrw, dinv, b2, P1, P2, N);      // h2 -> P2 (h1 dead)

    // ---- layer 3: 128 -> 64 ----
    transform<128, 64><<<cdiv((long long)N * 64, B), B, 0, stream>>>(P2, W3, P1, N);
    gather<64><<<cdiv((long long)N * 64, B), B, 0, stream>>>(
        rowptr, csrs, csrw, dinv, b3, P1, P2, N);      // h3 -> P2 (h2 dead)

    // ---- pooling + FC head ----
    pool<<<NG, 64, 0, stream>>>(P2, bat, Wfc, bfc, out, N);
}

// Round 3
// 777.027 us; speedup vs baseline: 7.9179x; 1.4136x over previous
//
#include <hip/hip_runtime.h>
#include <math.h>

#define NG 256

// ---------------- degree / cursor init ----------------
__global__ void zero1(int* deg, int n) {
    int i = blockIdx.x * blockDim.x + threadIdx.x;
    if (i < n) deg[i] = 0;
}

__global__ void hist(const int* __restrict__ dst, int* deg, int e) {
    int i = blockIdx.x * blockDim.x + threadIdx.x;
    if (i < e) atomicAdd(&deg[dst[i]], 1);
}

__global__ void make_dinv(const int* __restrict__ deg, float* dinv, int n) {
    int i = blockIdx.x * blockDim.x + threadIdx.x;
    if (i < n) dinv[i] = rsqrtf((float)deg[i] + 1.0f);  // +1 self-loop
}

// ---------------- exclusive scan of deg -> rowptr ----------------
__global__ void scan_blk(const int* __restrict__ deg, int* rowptr,
                         int* blksum, int n) {
    __shared__ int sh[1024];
    int tid = threadIdx.x;
    int g = blockIdx.x * 1024 + tid;
    int v = (g < n) ? deg[g] : 0;
    sh[tid] = v;
    __syncthreads();
    for (int off = 1; off < 1024; off <<= 1) {
        int t = (tid >= off) ? sh[tid - off] : 0;
        __syncthreads();
        sh[tid] += t;
        __syncthreads();
    }
    if (g < n) rowptr[g + 1] = sh[tid];            // block-local inclusive
    if (tid == 1023) blksum[blockIdx.x] = sh[1023];
}

__global__ void scan_sums(int* blksum, int nb) {
    if (blockIdx.x == 0 && threadIdx.x == 0) {
        int run = 0;
        for (int b = 0; b < nb; ++b) { run += blksum[b]; blksum[b] = run; }
    }
}

__global__ void scan_add(int* rowptr, const int* __restrict__ blksum, int n) {
    int g = blockIdx.x * blockDim.x + threadIdx.x;
    if (g == 0) rowptr[0] = 0;
    if (g < n) {
        int b = g >> 10;
        if (b > 0) rowptr[g + 1] += blksum[b - 1];
    }
}

__global__ void copy_cursor(const int* __restrict__ rowptr, int* cursor, int n) {
    int i = blockIdx.x * blockDim.x + threadIdx.x;
    if (i < n) cursor[i] = rowptr[i];
}

// ---------------- CSR fill (src list + precomputed edge weight) ----------
__global__ void fill_csr(const int* __restrict__ src, const int* __restrict__ dst,
                         const float* __restrict__ dinv, int* cursor,
                         int* csr_src, float* csr_w, int e) {
    int i = blockIdx.x * blockDim.x + threadIdx.x;
    if (i >= e) return;
    int s = src[i], d = dst[i];
    int pos = atomicAdd(&cursor[d], 1);
    csr_src[pos] = s;
    csr_w[pos] = dinv[s] * dinv[d];
}

// ---------------- layer-1 aggregate on raw x (5-dim), thread = node ------
__global__ void gather5(const int* __restrict__ rowptr,
                        const int* __restrict__ csrs,
                        const float* __restrict__ csrw,
                        const float* __restrict__ dinv,
                        const float* __restrict__ x,
                        float* __restrict__ z, int n) {
    int i = blockIdx.x * blockDim.x + threadIdx.x;
    if (i >= n) return;
    float di = dinv[i];
    float ws = di * di;
    const float* xr = x + (size_t)i * 5;
    float a0 = xr[0] * ws, a1 = xr[1] * ws, a2 = xr[2] * ws,
          a3 = xr[3] * ws, a4 = xr[4] * ws;
    int end = rowptr[i + 1];
    for (int j = rowptr[i]; j < end; ++j) {
        int s = csrs[j];
        float w = csrw[j];
        const float* r = x + (size_t)s * 5;
        a0 = fmaf(w, r[0], a0);
        a1 = fmaf(w, r[1], a1);
        a2 = fmaf(w, r[2], a2);
        a3 = fmaf(w, r[3], a3);
        a4 = fmaf(w, r[4], a4);
    }
    float* zr = z + (size_t)i * 5;
    zr[0] = a0; zr[1] = a1; zr[2] = a2; zr[3] = a3; zr[4] = a4;
}

// ---------------- dense transform, 8 outputs/thread ----------------------
// out[i][c*8..c*8+7] = (relu?)(xin[i] @ W + b); two float4 accumulators
template<int K, int DOUT, bool BR>
__global__ void transform8(const float* __restrict__ xin,
                           const float* __restrict__ W,
                           const float* __restrict__ b,
                           float* __restrict__ out, int n) {
    const int C = DOUT / 8;
    int tid = blockIdx.x * blockDim.x + threadIdx.x;
    int i = tid / C;
    int c = tid % C;
    if (i >= n) return;
    const float* row = xin + (size_t)i * K;
    float4 a0 = {0.f, 0.f, 0.f, 0.f};
    float4 a1 = {0.f, 0.f, 0.f, 0.f};
#pragma unroll 4
    for (int k = 0; k < K; ++k) {
        float v = row[k];
        const float* wp = W + (size_t)k * DOUT + c * 8;
        float4 w0 = *(const float4*)(wp);
        float4 w1 = *(const float4*)(wp + 4);
        a0.x = fmaf(v, w0.x, a0.x); a0.y = fmaf(v, w0.y, a0.y);
        a0.z = fmaf(v, w0.z, a0.z); a0.w = fmaf(v, w0.w, a0.w);
        a1.x = fmaf(v, w1.x, a1.x); a1.y = fmaf(v, w1.y, a1.y);
        a1.z = fmaf(v, w1.z, a1.z); a1.w = fmaf(v, w1.w, a1.w);
    }
    if (BR) {
        const float* bp = b + c * 8;
        float4 b0 = *(const float4*)(bp);
        float4 b1 = *(const float4*)(bp + 4);
        a0.x = fmaxf(a0.x + b0.x, 0.f); a0.y = fmaxf(a0.y + b0.y, 0.f);
        a0.z = fmaxf(a0.z + b0.z, 0.f); a0.w = fmaxf(a0.w + b0.w, 0.f);
        a1.x = fmaxf(a1.x + b1.x, 0.f); a1.y = fmaxf(a1.y + b1.y, 0.f);
        a1.z = fmaxf(a1.z + b1.z, 0.f); a1.w = fmaxf(a1.w + b1.w, 0.f);
    }
    float* op = out + (size_t)i * DOUT + c * 8;
    *(float4*)(op) = a0;
    *(float4*)(op + 4) = a1;
}

// ---------------- per-node gather (64-dim), wave = node ------------------
// z[i][f] = (relu? +bias?)( t[i][f]*dinv^2 + sum_in w * t[src][f] )
template<int DOUT, bool BR>
__global__ void gather(const int* __restrict__ rowptr,
                       const int* __restrict__ csrs,
                       const float* __restrict__ csrw,
                       const float* __restrict__ dinv,
                       const float* __restrict__ b,
                       const float* __restrict__ t,
                       float* __restrict__ h, int n) {
    int tid = blockIdx.x * blockDim.x + threadIdx.x;
    int i = tid / DOUT;
    int f = tid % DOUT;
    if (i >= n) return;
    float di = dinv[i];
    float acc = t[(size_t)i * DOUT + f] * di * di;
    if (BR) acc += b[f];
    float acc2 = 0.0f;
    int j = rowptr[i], end = rowptr[i + 1];
    for (; j + 3 < end; j += 4) {
        int s0 = csrs[j], s1 = csrs[j + 1], s2 = csrs[j + 2], s3 = csrs[j + 3];
        float w0 = csrw[j], w1 = csrw[j + 1], w2 = csrw[j + 2], w3 = csrw[j + 3];
        acc  = fmaf(w0, t[(size_t)s0 * DOUT + f], acc);
        acc2 = fmaf(w1, t[(size_t)s1 * DOUT + f], acc2);
        acc  = fmaf(w2, t[(size_t)s2 * DOUT + f], acc);
        acc2 = fmaf(w3, t[(size_t)s3 * DOUT + f], acc2);
    }
    for (; j < end; ++j)
        acc = fmaf(csrw[j], t[(size_t)csrs[j] * DOUT + f], acc);
    acc += acc2;
    h[(size_t)i * DOUT + f] = BR ? fmaxf(acc, 0.0f) : acc;
}

// ---------------- pooling + FC + sigmoid, one block per graph -----------
__global__ void pool(const float* __restrict__ h3, const int* __restrict__ batch,
                     const float* __restrict__ Wfc, const float* __restrict__ bfc,
                     float* __restrict__ out, int n) {
    int g = blockIdx.x;
    int lane = threadIdx.x;  // 64 threads = 1 wave = 64 features
    int lo = 0, hi = n;
    while (lo < hi) { int m = (lo + hi) >> 1; if (batch[m] < g) lo = m + 1; else hi = m; }
    int start = lo;
    hi = n;
    while (lo < hi) { int m = (lo + hi) >> 1; if (batch[m] < g + 1) lo = m + 1; else hi = m; }
    int end = lo;
    float acc = 0.0f;
    for (int m = start; m < end; ++m)
        acc += h3[(size_t)m * 64 + lane];
    float cnt = (float)(end - start);
    float val = acc / fmaxf(cnt, 1.0f);
    float v = val * Wfc[lane];
#pragma unroll
    for (int off = 32; off > 0; off >>= 1) v += __shfl_down(v, off, 64);
    if (lane == 0) out[g] = 1.0f / (1.0f + expf(-(v + bfc[0])));
}

static inline int cdiv(long long a, int b) { return (int)((a + b - 1) / b); }

extern "C" void kernel_launch(void* const* d_in, const int* in_sizes, int n_in,
                              void* d_out, int out_size, void* d_ws, size_t ws_size,
                              hipStream_t stream) {
    const float* x   = (const float*)d_in[0];
    const int*   ei  = (const int*)d_in[1];
    const int*   bat = (const int*)d_in[2];
    const float* W1  = (const float*)d_in[3];
    const float* b1  = (const float*)d_in[4];
    const float* W2  = (const float*)d_in[5];
    const float* b2  = (const float*)d_in[6];
    const float* W3  = (const float*)d_in[7];
    const float* b3  = (const float*)d_in[8];
    const float* Wfc = (const float*)d_in[9];
    const float* bfc = (const float*)d_in[10];
    float* out = (float*)d_out;

    const int N = in_sizes[0] / 5;   // 100000
    const int E = in_sizes[1] / 2;   // 1600000
    const int* src = ei;
    const int* dst = ei + E;

    // ---- workspace layout (4B elements, all 16B-aligned) ----
    float* ws    = (float*)d_ws;
    float* dinv  = ws;                         // N
    int*   deg   = (int*)(dinv + N);           // N
    int*   rowptr= deg + N;                    // N+4
    int*   cursor= rowptr + N + 4;             // N
    int*   blksum= cursor + N;                 // 128
    int*   csrs  = blksum + 128;               // E
    float* csrw  = (float*)(csrs + E);         // E
    float* A     = csrw + E;                   // N*128
    float* B     = A + (size_t)N * 128;        // N*128
    // total ~116 MB

    const int Blk = 256;
    const int NB = cdiv(N, 1024);

    // ---- norm + CSR build ----
    zero1<<<cdiv(N, Blk), Blk, 0, stream>>>(deg, N);
    hist<<<cdiv(E, Blk), Blk, 0, stream>>>(dst, deg, E);
    make_dinv<<<cdiv(N, Blk), Blk, 0, stream>>>(deg, dinv, N);
    scan_blk<<<NB, 1024, 0, stream>>>(deg, rowptr, blksum, N);
    scan_sums<<<1, 64, 0, stream>>>(blksum, NB);
    scan_add<<<cdiv(N, Blk), Blk, 0, stream>>>(rowptr, blksum, N);
    copy_cursor<<<cdiv(N, Blk), Blk, 0, stream>>>(rowptr, cursor, N);
    fill_csr<<<cdiv(E, Blk), Blk, 0, stream>>>(src, dst, dinv, cursor,
                                               csrs, csrw, E);

    // ---- layer 1: aggregate raw x (5-dim) then transform 5->64 + relu ----
    gather5<<<cdiv(N, Blk), Blk, 0, stream>>>(rowptr, csrs, csrw, dinv, x, A, N);
    transform8<5, 64, true><<<cdiv((long long)N * 8, Blk), Blk, 0, stream>>>(
        A, W1, b1, B, N);                                   // h1 -> B

    // ---- layer 2: aggregate h1 (64-dim) then transform 64->128 + relu ----
    gather<64, false><<<cdiv((long long)N * 64, Blk), Blk, 0, stream>>>(
        rowptr, csrs, csrw, dinv, nullptr, B, A, N);        // z2 -> A
    transform8<64, 128, true><<<cdiv((long long)N * 16, Blk), Blk, 0, stream>>>(
        A, W2, b2, B, N);                                   // h2 -> B

    // ---- layer 3: transform 128->64 then aggregate + bias + relu ----
    transform8<128, 64, false><<<cdiv((long long)N * 8, Blk), Blk, 0, stream>>>(
        B, W3, nullptr, A, N);                              // t3 -> A
    gather<64, true><<<cdiv((long long)N * 64, Blk), Blk, 0, stream>>>(
        rowptr, csrs, csrw, dinv, b3, A, B, N);             // h3 -> B

    // ---- pooling + FC head ----
    pool<<<NG, 64, 0, stream>>>(B, bat, Wfc, bfc, out, N);
}

// Round 4
// 560.164 us; speedup vs baseline: 10.9832x; 1.3871x over previous
//
#include <hip/hip_runtime.h>
#include <math.h>

#define NG 256

// ---------------- degree init / histogram / norm ----------------
__global__ void zero1(int* deg, int n) {
    int i = blockIdx.x * blockDim.x + threadIdx.x;
    if (i < n) deg[i] = 0;
}

__global__ void hist(const int* __restrict__ dst, int* deg, int e) {
    int i = blockIdx.x * blockDim.x + threadIdx.x;
    if (i < e) atomicAdd(&deg[dst[i]], 1);
}

__global__ void make_dinv(const int* __restrict__ deg, float* dinv, int n) {
    int i = blockIdx.x * blockDim.x + threadIdx.x;
    if (i < n) dinv[i] = rsqrtf((float)deg[i] + 1.0f);  // +1 self-loop
}

// ---------------- exclusive scan of deg -> rowptr ----------------
__global__ void scan_blk(const int* __restrict__ deg, int* rowptr,
                         int* blksum, int n) {
    __shared__ int sh[1024];
    int tid = threadIdx.x;
    int g = blockIdx.x * 1024 + tid;
    int v = (g < n) ? deg[g] : 0;
    sh[tid] = v;
    __syncthreads();
    for (int off = 1; off < 1024; off <<= 1) {
        int t = (tid >= off) ? sh[tid - off] : 0;
        __syncthreads();
        sh[tid] += t;
        __syncthreads();
    }
    if (g < n) rowptr[g + 1] = sh[tid];
    if (tid == 1023) blksum[blockIdx.x] = sh[1023];
}

__global__ void scan_sums(int* blksum, int nb) {
    if (blockIdx.x == 0 && threadIdx.x == 0) {
        int run = 0;
        for (int b = 0; b < nb; ++b) { run += blksum[b]; blksum[b] = run; }
    }
}

__global__ void scan_add(int* rowptr, const int* __restrict__ blksum, int n) {
    int g = blockIdx.x * blockDim.x + threadIdx.x;
    if (g == 0) rowptr[0] = 0;
    if (g < n) {
        int b = g >> 10;
        if (b > 0) rowptr[g + 1] += blksum[b - 1];
    }
}

__global__ void copy_cursor(const int* __restrict__ rowptr, int* cursor, int n) {
    int i = blockIdx.x * blockDim.x + threadIdx.x;
    if (i < n) cursor[i] = rowptr[i];
}

// ---------------- CSR fill: interleaved {src, weight} pairs -------------
__global__ void fill_csr(const int* __restrict__ src, const int* __restrict__ dst,
                         const float* __restrict__ dinv, int* cursor,
                         int2* edges, int e) {
    int i = blockIdx.x * blockDim.x + threadIdx.x;
    if (i >= e) return;
    int s = src[i], d = dst[i];
    int pos = atomicAdd(&cursor[d], 1);
    int2 ed;
    ed.x = s;
    ed.y = __float_as_int(dinv[s] * dinv[d]);
    edges[pos] = ed;
}

// ---------------- layer-1 aggregate on raw x (5-dim), thread = node ------
__global__ void gather5(const int* __restrict__ rowptr,
                        const int2* __restrict__ edges,
                        const float* __restrict__ dinv,
                        const float* __restrict__ x,
                        float* __restrict__ z, int n) {
    int i = blockIdx.x * blockDim.x + threadIdx.x;
    if (i >= n) return;
    float di = dinv[i];
    float ws = di * di;
    const float* xr = x + (size_t)i * 5;
    float a0 = xr[0] * ws, a1 = xr[1] * ws, a2 = xr[2] * ws,
          a3 = xr[3] * ws, a4 = xr[4] * ws;
    int end = rowptr[i + 1];
    for (int j = rowptr[i]; j < end; ++j) {
        int2 ed = edges[j];
        float w = __int_as_float(ed.y);
        const float* r = x + (size_t)ed.x * 5;
        a0 = fmaf(w, r[0], a0);
        a1 = fmaf(w, r[1], a1);
        a2 = fmaf(w, r[2], a2);
        a3 = fmaf(w, r[3], a3);
        a4 = fmaf(w, r[4], a4);
    }
    float* zr = z + (size_t)i * 5;
    zr[0] = a0; zr[1] = a1; zr[2] = a2; zr[3] = a3; zr[4] = a4;
}

// ------- dense transform, 8 outputs x NODES nodes per thread -------------
// W fragment loaded once per k-chunk, reused across NODES nodes.
template<int K, int DOUT, bool BR, int NODES>
__global__ void transformB(const float* __restrict__ xin,
                           const float* __restrict__ W,
                           const float* __restrict__ b,
                           float* __restrict__ out, int n) {
    const int C = DOUT / 8;
    int tid = blockIdx.x * blockDim.x + threadIdx.x;
    int grp = tid / C;
    int c = tid % C;
    int i0 = grp * NODES;
    if (i0 >= n) return;
    float acc[NODES][8];
#pragma unroll
    for (int nn = 0; nn < NODES; ++nn)
#pragma unroll
        for (int q = 0; q < 8; ++q) acc[nn][q] = 0.0f;

    static_assert(K % 4 == 0, "K multiple of 4");
    for (int k0 = 0; k0 < K; k0 += 4) {
        float4 r[NODES];
#pragma unroll
        for (int nn = 0; nn < NODES; ++nn) {
            int idx = i0 + nn < n ? i0 + nn : n - 1;  // clamp (redundant read)
            r[nn] = *(const float4*)(xin + (size_t)idx * K + k0);
        }
#pragma unroll
        for (int kk = 0; kk < 4; ++kk) {
            const float* wp = W + (size_t)(k0 + kk) * DOUT + c * 8;
            float4 w0 = *(const float4*)(wp);
            float4 w1 = *(const float4*)(wp + 4);
#pragma unroll
            for (int nn = 0; nn < NODES; ++nn) {
                float v = (&r[nn].x)[kk];
                acc[nn][0] = fmaf(v, w0.x, acc[nn][0]);
                acc[nn][1] = fmaf(v, w0.y, acc[nn][1]);
                acc[nn][2] = fmaf(v, w0.z, acc[nn][2]);
                acc[nn][3] = fmaf(v, w0.w, acc[nn][3]);
                acc[nn][4] = fmaf(v, w1.x, acc[nn][4]);
                acc[nn][5] = fmaf(v, w1.y, acc[nn][5]);
                acc[nn][6] = fmaf(v, w1.z, acc[nn][6]);
                acc[nn][7] = fmaf(v, w1.w, acc[nn][7]);
            }
        }
    }
    float4 b0, b1;
    if (BR) {
        b0 = *(const float4*)(b + c * 8);
        b1 = *(const float4*)(b + c * 8 + 4);
    }
#pragma unroll
    for (int nn = 0; nn < NODES; ++nn) {
        if (i0 + nn >= n) break;
        float4 o0, o1;
        o0.x = acc[nn][0]; o0.y = acc[nn][1]; o0.z = acc[nn][2]; o0.w = acc[nn][3];
        o1.x = acc[nn][4]; o1.y = acc[nn][5]; o1.z = acc[nn][6]; o1.w = acc[nn][7];
        if (BR) {
            o0.x = fmaxf(o0.x + b0.x, 0.f); o0.y = fmaxf(o0.y + b0.y, 0.f);
            o0.z = fmaxf(o0.z + b0.z, 0.f); o0.w = fmaxf(o0.w + b0.w, 0.f);
            o1.x = fmaxf(o1.x + b1.x, 0.f); o1.y = fmaxf(o1.y + b1.y, 0.f);
            o1.z = fmaxf(o1.z + b1.z, 0.f); o1.w = fmaxf(o1.w + b1.w, 0.f);
        }
        float* op = out + (size_t)(i0 + nn) * DOUT + c * 8;
        *(float4*)(op) = o0;
        *(float4*)(op + 4) = o1;
    }
}

// ---- K=5 variant (layer 1): rows fully register-resident ---------------
template<int DOUT, bool BR, int NODES>
__global__ void transformB5(const float* __restrict__ xin,
                            const float* __restrict__ W,
                            const float* __restrict__ b,
                            float* __restrict__ out, int n) {
    const int C = DOUT / 8;
    int tid = blockIdx.x * blockDim.x + threadIdx.x;
    int grp = tid / C;
    int c = tid % C;
    int i0 = grp * NODES;
    if (i0 >= n) return;
    float r[NODES][5];
#pragma unroll
    for (int nn = 0; nn < NODES; ++nn) {
        int idx = i0 + nn < n ? i0 + nn : n - 1;
        const float* row = xin + (size_t)idx * 5;
#pragma unroll
        for (int k = 0; k < 5; ++k) r[nn][k] = row[k];
    }
    float acc[NODES][8];
#pragma unroll
    for (int nn = 0; nn < NODES; ++nn)
#pragma unroll
        for (int q = 0; q < 8; ++q) acc[nn][q] = 0.0f;
#pragma unroll
    for (int k = 0; k < 5; ++k) {
        const float* wp = W + (size_t)k * DOUT + c * 8;
        float4 w0 = *(const float4*)(wp);
        float4 w1 = *(const float4*)(wp + 4);
#pragma unroll
        for (int nn = 0; nn < NODES; ++nn) {
            float v = r[nn][k];
            acc[nn][0] = fmaf(v, w0.x, acc[nn][0]);
            acc[nn][1] = fmaf(v, w0.y, acc[nn][1]);
            acc[nn][2] = fmaf(v, w0.z, acc[nn][2]);
            acc[nn][3] = fmaf(v, w0.w, acc[nn][3]);
            acc[nn][4] = fmaf(v, w1.x, acc[nn][4]);
            acc[nn][5] = fmaf(v, w1.y, acc[nn][5]);
            acc[nn][6] = fmaf(v, w1.z, acc[nn][6]);
            acc[nn][7] = fmaf(v, w1.w, acc[nn][7]);
        }
    }
    float4 b0, b1;
    if (BR) {
        b0 = *(const float4*)(b + c * 8);
        b1 = *(const float4*)(b + c * 8 + 4);
    }
#pragma unroll
    for (int nn = 0; nn < NODES; ++nn) {
        if (i0 + nn >= n) break;
        float4 o0, o1;
        o0.x = acc[nn][0]; o0.y = acc[nn][1]; o0.z = acc[nn][2]; o0.w = acc[nn][3];
        o1.x = acc[nn][4]; o1.y = acc[nn][5]; o1.z = acc[nn][6]; o1.w = acc[nn][7];
        if (BR) {
            o0.x = fmaxf(o0.x + b0.x, 0.f); o0.y = fmaxf(o0.y + b0.y, 0.f);
            o0.z = fmaxf(o0.z + b0.z, 0.f); o0.w = fmaxf(o0.w + b0.w, 0.f);
            o1.x = fmaxf(o1.x + b1.x, 0.f); o1.y = fmaxf(o1.y + b1.y, 0.f);
            o1.z = fmaxf(o1.z + b1.z, 0.f); o1.w = fmaxf(o1.w + b1.w, 0.f);
        }
        float* op = out + (size_t)(i0 + nn) * DOUT + c * 8;
        *(float4*)(op) = o0;
        *(float4*)(op + 4) = o1;
    }
}

// ---------------- per-node gather (64-dim), wave = node ------------------
template<int DOUT, bool BR>
__global__ void gather(const int* __restrict__ rowptr,
                       const int2* __restrict__ edges,
                       const float* __restrict__ dinv,
                       const float* __restrict__ b,
                       const float* __restrict__ t,
                       float* __restrict__ h, int n) {
    int tid = blockIdx.x * blockDim.x + threadIdx.x;
    int i = tid / DOUT;
    int f = tid % DOUT;
    if (i >= n) return;
    float di = dinv[i];
    float a0 = t[(size_t)i * DOUT + f] * di * di;
    if (BR) a0 += b[f];
    float a1 = 0.f, a2 = 0.f, a3 = 0.f;
    int j = rowptr[i], end = rowptr[i + 1];
    for (; j + 7 < end; j += 8) {
        int2 e0 = edges[j], e1 = edges[j+1], e2 = edges[j+2], e3 = edges[j+3];
        int2 e4 = edges[j+4], e5 = edges[j+5], e6 = edges[j+6], e7 = edges[j+7];
        a0 = fmaf(__int_as_float(e0.y), t[(size_t)e0.x * DOUT + f], a0);
        a1 = fmaf(__int_as_float(e1.y), t[(size_t)e1.x * DOUT + f], a1);
        a2 = fmaf(__int_as_float(e2.y), t[(size_t)e2.x * DOUT + f], a2);
        a3 = fmaf(__int_as_float(e3.y), t[(size_t)e3.x * DOUT + f], a3);
        a0 = fmaf(__int_as_float(e4.y), t[(size_t)e4.x * DOUT + f], a0);
        a1 = fmaf(__int_as_float(e5.y), t[(size_t)e5.x * DOUT + f], a1);
        a2 = fmaf(__int_as_float(e6.y), t[(size_t)e6.x * DOUT + f], a2);
        a3 = fmaf(__int_as_float(e7.y), t[(size_t)e7.x * DOUT + f], a3);
    }
    for (; j < end; ++j) {
        int2 ed = edges[j];
        a0 = fmaf(__int_as_float(ed.y), t[(size_t)ed.x * DOUT + f], a0);
    }
    float acc = (a0 + a1) + (a2 + a3);
    h[(size_t)i * DOUT + f] = BR ? fmaxf(acc, 0.0f) : acc;
}

// ------- pooling + FC + sigmoid: 4 waves per graph, LDS combine ---------
__global__ void pool(const float* __restrict__ h3, const int* __restrict__ batch,
                     const float* __restrict__ Wfc, const float* __restrict__ bfc,
                     float* __restrict__ out, int n) {
    int g = blockIdx.x;
    int lane = threadIdx.x & 63;
    int w = threadIdx.x >> 6;  // 0..3
    int lo = 0, hi = n;
    while (lo < hi) { int m = (lo + hi) >> 1; if (batch[m] < g) lo = m + 1; else hi = m; }
    int start = lo;
    hi = n;
    while (lo < hi) { int m = (lo + hi) >> 1; if (batch[m] < g + 1) lo = m + 1; else hi = m; }
    int end = lo;
    float a0 = 0.f, a1 = 0.f, a2 = 0.f, a3 = 0.f;
    int m = start + w;
    for (; m + 12 < end; m += 16) {
        a0 += h3[(size_t)m * 64 + lane];
        a1 += h3[(size_t)(m + 4) * 64 + lane];
        a2 += h3[(size_t)(m + 8) * 64 + lane];
        a3 += h3[(size_t)(m + 12) * 64 + lane];
    }
    for (; m < end; m += 4) a0 += h3[(size_t)m * 64 + lane];
    __shared__ float sh[4][64];
    sh[w][lane] = (a0 + a1) + (a2 + a3);
    __syncthreads();
    if (w == 0) {
        float v = (sh[0][lane] + sh[1][lane]) + (sh[2][lane] + sh[3][lane]);
        float cnt = (float)(end - start);
        v = (v / fmaxf(cnt, 1.0f)) * Wfc[lane];
#pragma unroll
        for (int off = 32; off > 0; off >>= 1) v += __shfl_down(v, off, 64);
        if (lane == 0) out[g] = 1.0f / (1.0f + expf(-(v + bfc[0])));
    }
}

static inline int cdiv(long long a, int b) { return (int)((a + b - 1) / b); }

extern "C" void kernel_launch(void* const* d_in, const int* in_sizes, int n_in,
                              void* d_out, int out_size, void* d_ws, size_t ws_size,
                              hipStream_t stream) {
    const float* x   = (const float*)d_in[0];
    const int*   ei  = (const int*)d_in[1];
    const int*   bat = (const int*)d_in[2];
    const float* W1  = (const float*)d_in[3];
    const float* b1  = (const float*)d_in[4];
    const float* W2  = (const float*)d_in[5];
    const float* b2  = (const float*)d_in[6];
    const float* W3  = (const float*)d_in[7];
    const float* b3  = (const float*)d_in[8];
    const float* Wfc = (const float*)d_in[9];
    const float* bfc = (const float*)d_in[10];
    float* out = (float*)d_out;

    const int N = in_sizes[0] / 5;   // 100000
    const int E = in_sizes[1] / 2;   // 1600000
    const int* src = ei;
    const int* dst = ei + E;

    // ---- workspace layout (4B elements, 16B-aligned blocks) ----
    float* ws    = (float*)d_ws;
    float* dinv  = ws;                          // N
    int*   deg   = (int*)(dinv + N);            // N
    int*   rowptr= deg + N;                     // N+4
    int*   cursor= rowptr + N + 4;              // N
    int*   blksum= cursor + N;                  // 128
    int2*  edges = (int2*)(blksum + 128);       // E pairs (8B each)
    float* A     = (float*)(edges + E);         // N*128
    float* B     = A + (size_t)N * 128;         // N*128

    const int Blk = 256;
    const int NB = cdiv(N, 1024);

    // ---- norm + CSR build ----
    zero1<<<cdiv(N, Blk), Blk, 0, stream>>>(deg, N);
    hist<<<cdiv(E, Blk), Blk, 0, stream>>>(dst, deg, E);
    make_dinv<<<cdiv(N, Blk), Blk, 0, stream>>>(deg, dinv, N);
    scan_blk<<<NB, 1024, 0, stream>>>(deg, rowptr, blksum, N);
    scan_sums<<<1, 64, 0, stream>>>(blksum, NB);
    scan_add<<<cdiv(N, Blk), Blk, 0, stream>>>(rowptr, blksum, N);
    copy_cursor<<<cdiv(N, Blk), Blk, 0, stream>>>(rowptr, cursor, N);
    fill_csr<<<cdiv(E, Blk), Blk, 0, stream>>>(src, dst, dinv, cursor, edges, E);

    // ---- layer 1: aggregate raw x (5-dim), then 5->64 + relu ----
    gather5<<<cdiv(N, Blk), Blk, 0, stream>>>(rowptr, edges, dinv, x, A, N);
    transformB5<64, true, 4><<<cdiv((long long)cdiv(N, 4) * 8, Blk), Blk, 0, stream>>>(
        A, W1, b1, B, N);                                   // h1 -> B

    // ---- layer 2: aggregate h1 (64-dim), then 64->128 + relu ----
    gather<64, false><<<cdiv((long long)N * 64, Blk), Blk, 0, stream>>>(
        rowptr, edges, dinv, nullptr, B, A, N);             // z2 -> A
    transformB<64, 128, true, 4><<<cdiv((long long)cdiv(N, 4) * 16, Blk), Blk, 0, stream>>>(
        A, W2, b2, B, N);                                   // h2 -> B

    // ---- layer 3: 128->64 first, then aggregate + bias + relu ----
    transformB<128, 64, false, 4><<<cdiv((long long)cdiv(N, 4) * 8, Blk), Blk, 0, stream>>>(
        B, W3, nullptr, A, N);                              // t3 -> A
    gather<64, true><<<cdiv((long long)N * 64, Blk), Blk, 0, stream>>>(
        rowptr, edges, dinv, b3, A, B, N);                  // h3 -> B

    // ---- pooling + FC head ----
    pool<<<NG, 256, 0, stream>>>(B, bat, Wfc, bfc, out, N);
}